// Round 5
// baseline (351.940 us; speedup 1.0000x reference)
//
#include <hip/hip_runtime.h>
#include <hip/hip_bf16.h>

typedef __hip_bfloat16 bf16;
typedef float f32x4 __attribute__((ext_vector_type(4)));

__device__ __forceinline__ float b2f(bf16 x) { return __bfloat162float(x); }

// Inputs proved float32 (R1/R2 of prior session); bf16 path kept as insurance.
template<bool F32>
__device__ __forceinline__ float ld(const void* p, size_t i) {
  if constexpr (F32) return ((const float*)p)[i];
  else return b2f(((const bf16*)p)[i]);
}

template<bool F32>
__device__ __forceinline__ void ld4(const void* p, size_t i, float v[4]) {
  if constexpr (F32) {
    const float4 a = *(const float4*)((const float*)p + i);
    v[0]=a.x; v[1]=a.y; v[2]=a.z; v[3]=a.w;
  } else {
    union { uint2 u; bf16 h[4]; } t;
    t.u = *(const uint2*)((const bf16*)p + i);
    #pragma unroll
    for (int c = 0; c < 4; ++c) v[c] = b2f(t.h[c]);
  }
}

template<bool F32>
__device__ __forceinline__ void ld8(const void* p, size_t i, float v[8]) {
  if constexpr (F32) {
    const float4 a = *(const float4*)((const float*)p + i);
    const float4 b = *(const float4*)((const float*)p + i + 4);
    v[0]=a.x; v[1]=a.y; v[2]=a.z; v[3]=a.w;
    v[4]=b.x; v[5]=b.y; v[6]=b.z; v[7]=b.w;
  } else {
    union { uint4 u; bf16 h[8]; } t;
    t.u = *(const uint4*)((const bf16*)p + i);
    #pragma unroll
    for (int c = 0; c < 8; ++c) v[c] = b2f(t.h[c]);
  }
}

// NT loads: M1-3 are single-use; keep them from evicting W1-3 out of L2/L3.
// (NT *stores* removed: R2 showed 1.6x write amplification, 99->160 MB.)
template<bool F32>
__device__ __forceinline__ void ld8nt(const void* p, size_t i, float v[8]) {
  if constexpr (F32) {
    const f32x4* q = (const f32x4*)((const float*)p + i);
    const f32x4 a = __builtin_nontemporal_load(q);
    const f32x4 b = __builtin_nontemporal_load(q + 1);
    v[0]=a[0]; v[1]=a[1]; v[2]=a[2]; v[3]=a[3];
    v[4]=b[0]; v[5]=b[1]; v[6]=b[2]; v[7]=b[3];
  } else {
    ld8<false>(p, i, v);
  }
}

__device__ __forceinline__ float plast(float Ec, float Ebl) {
  const float Eb0 = (Ebl == 0.f) ? Ec : Ebl;          // bmask logic
  const float Eb  = Eb0 * 0.95f + 0.05f * Ec;         // EMA_SPEED
  const float adv = Ec - Eb;                          // REW_SENS = 1
  const float R   = -adv * rsqrtf(adv*adv + 1e-6f);   // rms_norm size-1 axis
  return (Eb > 0.f) ? (1.f - R) : 0.f;                // plasticity * mask
}

// B=16, N=128, D=64 ; nodes = B*N = 2048
// ws layout (floats):
//   q @0 | k @131072 | err @262144 | pl @393216
//   magn @524288 (2048, per-node) | mag @526336 (16, per-batch)
//   stats @526352 (2) | flag @526354 (1 int)

// ---------------- Kernel 1: q, k, prediction matvecs + per-node |state| -----
// One wave per (node, matrix): 6144 waves = 1536 blocks x 4. mat-major decode
// (node = wid & 2047, mat = wid >> 11). Lane = (jg, cq): jg = lane>>4 owns
// rows [jg*16, jg*16+16), cq = lane&15 owns cols 4*cq..+3. All 16 ld4 per
// thread issued in ONE batch (64-VGPR buffer) -> ~16 loads in flight.
template<bool F32>
__device__ __forceinline__ void k1_wave(
    const void* state, const void* W1, const void* W2, const void* W3,
    float* qw, float* kw, float* magn, float* out_pred,
    int node, int mat, int lane)
{
  const float st = ld<F32>(state, (size_t)node*64 + lane);
  const int jg = lane >> 4, cq = lane & 15;
  const int c0 = cq * 4;
  const size_t nb = (size_t)node*4096 + (size_t)jg*1024 + c0;  // row jg*16, col c0
  const void* W = (mat == 0) ? W3 : (mat == 1) ? W2 : W1;

  float acc[4] = {0.f, 0.f, 0.f, 0.f};
  float buf[16][4];
  #pragma unroll
  for (int jj = 0; jj < 16; ++jj) ld4<F32>(W, nb + (size_t)jj*64, buf[jj]);
  #pragma unroll
  for (int jj = 0; jj < 16; ++jj) {
    const float sj = __shfl(st, jg*16 + jj, 64);
    #pragma unroll
    for (int cc = 0; cc < 4; ++cc) acc[cc] += sj * buf[jj][cc];
  }
  // butterfly over the 4 jg groups: every lane ends with the full sum for cq
  #pragma unroll
  for (int cc = 0; cc < 4; ++cc) {
    acc[cc] += __shfl_xor(acc[cc], 16, 64);
    acc[cc] += __shfl_xor(acc[cc], 32, 64);
  }

  if (mat == 2) {
    // per-node state magnitude (atomic-free; reduced to mag[b] in k2)
    float am = fabsf(st);
    #pragma unroll
    for (int s = 32; s; s >>= 1) am += __shfl_xor(am, s, 64);
    if (lane == 0) magn[node] = am;
    if (jg == 0) {
      float pr[4];
      #pragma unroll
      for (int cc = 0; cc < 4; ++cc) {
        const float raw = acc[cc] - tanhf(acc[cc]) * 0.6f;          // UNTANH
        pr[cc] = tanhf(raw) * 1.8477590650225735f;                  // sqrt(2+sqrt2)
      }
      *(float4*)(out_pred + (size_t)node*64 + c0) = make_float4(pr[0], pr[1], pr[2], pr[3]);
    }
  } else if (jg == 0) {
    float* dst = (mat == 0) ? qw : kw;
    *(float4*)(dst + (size_t)node*64 + c0) = make_float4(acc[0], acc[1], acc[2], acc[3]);
  }
}

__global__ __launch_bounds__(256) void k1_qkpred(
    const void* __restrict__ state,
    const void* __restrict__ W1, const void* __restrict__ W2,
    const void* __restrict__ W3,
    float* __restrict__ qw, float* __restrict__ kw,
    float* __restrict__ magn, float* __restrict__ out_pred,
    int* __restrict__ flagws, float* __restrict__ stats)
{
  const int tid = threadIdx.x;
  const int w = tid >> 6, lane = tid & 63;
  // dtype detect: every wave samples the SAME 1024 bf16 elements, so all
  // ballots agree without any cross-wave communication.
  bool huge = false;
  for (int i = lane; i < 1024; i += 64) {
    const float x = b2f(((const bf16*)state)[i]);
    if (!(fabsf(x) < 1e5f)) huge = true;   // catches NaN too
  }
  const bool f32 = (__ballot(huge) != 0ull);   // huge-as-bf16 => really float32
  if (blockIdx.x == 0 && tid == 0) {
    *flagws = f32 ? 1 : 0;                 // for k2/k3
    stats[0] = 0.f; stats[1] = 0.f;        // zeroed before k2's atomics (in-stream order)
  }
  const int wid = blockIdx.x * 4 + w;
  const int node = wid & 2047, mat = wid >> 11;
  if (f32) k1_wave<true >(state, W1, W2, W3, qw, kw, magn, out_pred, node, mat, lane);
  else     k1_wave<false>(state, W1, W2, W3, qw, kw, magn, out_pred, node, mat, lane);
}

// ---------------- Kernel 2: attention row, A_new, target, err, plasticity ---
// 512 blocks = 16 batches x 32 tiles of 4 rows; 256 threads = 4 waves, ONE
// WAVE PER ROW (lane owns m = lane and lane+64). 2 blocks/CU x 4 waves = 8
// waves/CU (2x the R4 tile) and zero cross-wave reductions: row softmax and
// err softmax are 64-lane butterflies; the A row is wave-local (LDS write ->
// same-wave read, no barrier). k slice staged once per block, stride-65
// padded: dot reads are 2-way bank aliases (free).
template<bool F32>
__device__ __forceinline__ void k2_body(
    const float* qw, const float* kw, const float* predw,
    const void* noiseA, const void* Aold, const void* outp,
    const void* eye, const void* stomach, const void* Ebase,
    const float* magn, float* mag,
    float* errw, float* plw, float* stats,
    float* out_target, float* out_A,
    float* s_k, float* s_q, float* s_A)
{
  const int bidx = blockIdx.x;
  const int b = bidx >> 5;            // 32 tiles per batch
  const int n0 = (bidx & 31) * 4;     // 4 rows per block
  const int tid = threadIdx.x;
  const int w = tid >> 6, lane = tid & 63;

  if ((bidx & 31) == 0 && tid < 64) {  // mag[b] = sum of the batch's node mags
    float v = magn[b*128 + tid] + magn[b*128 + 64 + tid];
    #pragma unroll
    for (int s = 32; s; s >>= 1) v += __shfl_xor(v, s, 64);
    if (tid == 0) mag[b] = v;
  }

  { // stage k slice [128][64] -> LDS [128][65] (padded), q rows [4][64]
    const float* kwb = kw + (size_t)b * 8192;
    #pragma unroll
    for (int it = 0; it < 8; ++it) {
      const int idx = it*256 + tid;          // float4 index, 0..2047
      const int m = idx >> 4, dq = idx & 15;
      const float4 v = *(const float4*)(kwb + (size_t)idx * 4);
      float* dst = &s_k[m*65 + dq*4];
      dst[0] = v.x; dst[1] = v.y; dst[2] = v.z; dst[3] = v.w;
    }
    if (tid < 64) {
      const int rr = tid >> 4, dq = tid & 15;
      *(float4*)&s_q[rr*64 + dq*4] =
          *(const float4*)(qw + ((size_t)(b*128 + n0 + rr))*64 + dq*4);
    }
  }
  __syncthreads();

  const int n = n0 + w;
  const size_t node = (size_t)b*128 + n;

  // dots raw_A[n, m] for m = lane, lane+64
  float d0 = 0.f, d1 = 0.f;
  {
    const float* qrow = s_q + w*64;
    const float* kr0 = s_k + lane*65;          // banks (lane+j)%32: 2-way, free
    const float* kr1 = s_k + (lane + 64)*65;   // 64*65 % 32 == 0: same pattern
    #pragma unroll 8
    for (int j = 0; j < 64; ++j) {
      const float qv = qrow[j];
      d0 += qv * kr0[j];
      d1 += qv * kr1[j];
    }
  }
  const float raw0 = d0*0.125f + 1e-5f*ld<F32>(noiseA, node*128 + lane);
  const float raw1 = d1*0.125f + 1e-5f*ld<F32>(noiseA, node*128 + lane + 64);

  // row softmax over 128 via 64-lane butterflies (2 values/lane)
  float rmx = fmaxf(raw0, raw1);
  #pragma unroll
  for (int s = 32; s; s >>= 1) rmx = fmaxf(rmx, __shfl_xor(rmx, s, 64));
  const float e0x = expf(raw0 - rmx), e1x = expf(raw1 - rmx);
  float S = e0x + e1x;
  #pragma unroll
  for (int s = 32; s; s >>= 1) S += __shfl_xor(S, s, 64);
  const float thr = 0.007751937984496124f;     // 1/(N+1)
  const float ek0 = ((e0x/S > thr) || (raw0 == rmx)) ? e0x : 0.f;
  const float ek1 = ((e1x/S > thr) || (raw1 == rmx)) ? e1x : 0.f;
  float Sk = ek0 + ek1;
  #pragma unroll
  for (int s = 32; s; s >>= 1) Sk += __shfl_xor(Sk, s, 64);
  const float A0 = (n < 2) ? 0.f
                 : 0.99f*ld<F32>(Aold, node*128 + lane)      + 0.01f*(ek0/Sk);
  const float A1 = (n < 2) ? 0.f
                 : 0.99f*ld<F32>(Aold, node*128 + lane + 64) + 0.01f*(ek1/Sk);
  out_A[node*128 + lane]      = A0;
  out_A[node*128 + lane + 64] = A1;
  s_A[w*128 + lane]      = A0;   // wave-local: written and read by the same
  s_A[w*128 + lane + 64] = A1;   // wave -> no __syncthreads needed

  // target row: lane owns d = lane
  float t0;
  if (n == 0)      t0 = ld<F32>(eye, (size_t)b*64 + lane);
  else if (n == 1) t0 = ld<F32>(stomach, (size_t)b*64 + lane);
  else {
    t0 = 0.f;
    const float* arow = s_A + w*128;
    const size_t ob = (size_t)b * 8192;
    #pragma unroll 8
    for (int m = 0; m < 128; ++m)
      t0 += arow[m] * ld<F32>(outp, ob + (size_t)m*64 + lane);
  }
  out_target[node*64 + lane] = t0;
  const float er = predw[node*64 + lane] - t0;
  errw[node*64 + lane] = er;

  // E_curr = softmax(err over d=64), then plasticity*mask
  float mx = er;
  #pragma unroll
  for (int s = 32; s; s >>= 1) mx = fmaxf(mx, __shfl_xor(mx, s, 64));
  const float ee = expf(er - mx);
  float ss = ee;
  #pragma unroll
  for (int s = 32; s; s >>= 1) ss += __shfl_xor(ss, s, 64);
  plw[node*64 + lane] = plast(ee/ss, ld<F32>(Ebase, node*64 + lane));

  // global err stats (for std, ddof=1)
  float se = er, sq2 = er*er;
  #pragma unroll
  for (int s = 32; s; s >>= 1) { se += __shfl_xor(se, s, 64); sq2 += __shfl_xor(sq2, s, 64); }
  if (lane == 0) { atomicAdd(&stats[0], se); atomicAdd(&stats[1], sq2); }
}

__global__ __launch_bounds__(256) void k2_attn(
    const int* __restrict__ flag,
    const float* __restrict__ qw, const float* __restrict__ kw,
    const float* __restrict__ predw,
    const void* __restrict__ noiseA, const void* __restrict__ Aold,
    const void* __restrict__ outp,
    const void* __restrict__ eye, const void* __restrict__ stomach,
    const void* __restrict__ Ebase,
    const float* __restrict__ magn, float* __restrict__ mag,
    float* __restrict__ errw, float* __restrict__ plw,
    float* __restrict__ stats,
    float* __restrict__ out_target, float* __restrict__ out_A)
{
  __shared__ alignas(16) float s_k[128*65];   // padded: conflict-free strided reads
  __shared__ alignas(16) float s_q[4*64];
  __shared__ alignas(16) float s_A[4*128];
  if (*flag) k2_body<true >(qw,kw,predw,noiseA,Aold,outp,eye,stomach,Ebase,magn,mag,errw,plw,stats,out_target,out_A,s_k,s_q,s_A);
  else       k2_body<false>(qw,kw,predw,noiseA,Aold,outp,eye,stomach,Ebase,magn,mag,errw,plw,stats,out_target,out_A,s_k,s_q,s_A);
}

// ---------------- Kernel 3: grads, momentum, W update + row rms-norm ---------
// Barrier-free, LDS-free: each of the 8 waves redundantly computes the node's
// 64-wide coefficient vectors (err, ns, pe, c, g) in registers via 64-lane
// butterflies (the 5 small loads are L1-hot, issued BEFORE the 12 big loads
// so prologue math runs under vmcnt(12), not vmcnt(0)). Per-column coeffs
// fetched by __shfl. Waves are fully independent -> no barrier convoy.
template<bool F32>
__device__ __forceinline__ void k3_body(
    const float* errw, const float* plw,
    const void* state, const void* n1raw, const void* n2raw,
    const float* mag, const float* stats, const int* stepc,
    const void* W1, const void* W2, const void* W3,
    const void* M1, const void* M2, const void* M3,
    float* oW1, float* oW2, float* oW3)
{
  const int node = blockIdx.x;
  const int b = node >> 7;
  const int tid = threadIdx.x;
  const int lane = tid & 63;
  const int r = tid >> 3;          // output row 0..63
  const int l8 = tid & 7;          // column group: j = l8*8..+7

  // --- small per-lane loads first (index = lane, i.e. vector element) ---
  const size_t sb = (size_t)node*64 + lane;
  const float e_i  = errw[sb];
  const float pl_i = plw[sb];
  const float st_i = ld<F32>(state, sb);
  const float n1_i = ld<F32>(n1raw, sb);
  const float n2_i = ld<F32>(n2raw, sb);
  const float magb = mag[b];
  const float S1 = stats[0], S2 = stats[1];
  const float scv = (float)stepc[0] + 1.f;

  // --- big loads (12 x dwordx4 per thread) ---
  const size_t off = (size_t)node*4096 + (size_t)r*64 + (size_t)l8*8;
  float w1v[8], w2v[8], w3v[8], m1v[8], m2v[8], m3v[8];
  ld8  <F32>(W1, off, w1v); ld8  <F32>(W2, off, w2v); ld8  <F32>(W3, off, w3v);
  ld8nt<F32>(M1, off, m1v); ld8nt<F32>(M2, off, m2v); ld8nt<F32>(M3, off, m3v);

  // --- prologue math (depends only on the small loads) ---
  const float Mn = 131072.f;                           // B*N*D
  const float var = (S2 - S1*S1/Mn) / (Mn - 1.f);      // ddof=1
  const float stdv = sqrtf(fmaxf(var, 0.f));
  const float ns_i = st_i + n1_i / (1.f + magb)
                   + n2_i * stdv * 0.8f;               // NOISE_SCALE
  float e2 = e_i*e_i, q2 = ns_i*ns_i;
  #pragma unroll
  for (int s = 32; s; s >>= 1) { e2 += __shfl_xor(e2, s, 64); q2 += __shfl_xor(q2, s, 64); }
  // rms_norm(lg) factorizes: mean(lg^2) = (sum err^2)(sum ns^2)/4096
  const float c_i  = -ns_i * rsqrtf(e2 * q2 * (1.f/4096.f) + 1e-6f);
  const float pe_i = pl_i * e_i;                       // plasticity*mask*err
  const float center = fmodf(scv * 0.5f, 64.f);        // SPEED
  float dff = fabsf((float)lane - center);
  dff = fminf(dff, 64.f - dff);
  const float g_i = expf(-dff*dff * (1.f/0.020001f));  // 2*WIDTH^2+1e-6

  const float pe = __shfl(pe_i, r, 64);                // row coefficient
  float cj[8], gj[8];
  #pragma unroll
  for (int cc = 0; cc < 8; ++cc) {
    const int j = l8*8 + cc;
    cj[cc] = __shfl(c_i, j, 64);
    gj[cc] = __shfl(g_i, j, 64);
  }

  // --- main update (depends on big loads) ---
  float t1[8], t2[8], t3[8];
  float ss1 = 0.f, ss2 = 0.f, ss3 = 0.f;
  #pragma unroll
  for (int cc = 0; cc < 8; ++cc) {
    const float lgterm = pe * cj[cc];                  // p_i * lg_ij
    const float g = gj[cc];
    const float g1 = lgterm + 0.01f*w3v[cc] - 0.01f*w1v[cc];  // LAT_DECAY, WD
    const float g2 = lgterm + 0.01f*w1v[cc] - 0.01f*w2v[cc];
    const float g3 = lgterm + 0.01f*w2v[cc] - 0.01f*w3v[cc];
    const float v1 = w1v[cc] + 0.0033f*(0.4f*m1v[cc] + 0.6f*g1*g); // LR, MOMENTUM
    const float v2 = w2v[cc] + 0.0033f*(0.4f*m2v[cc] + 0.6f*g2*g);
    const float v3 = w3v[cc] + 0.0033f*(0.4f*m3v[cc] + 0.6f*g3*g);
    t1[cc] = v1; t2[cc] = v2; t3[cc] = v3;
    ss1 += v1*v1; ss2 += v2*v2; ss3 += v3*v3;
  }
  #pragma unroll
  for (int s = 1; s <= 4; s <<= 1) {
    ss1 += __shfl_xor(ss1, s, 64);
    ss2 += __shfl_xor(ss2, s, 64);
    ss3 += __shfl_xor(ss3, s, 64);
  }
  const float r1 = rsqrtf(ss1*(1.f/64.f) + 1e-6f);     // row rms over j
  const float r2 = rsqrtf(ss2*(1.f/64.f) + 1e-6f);
  const float r3 = rsqrtf(ss3*(1.f/64.f) + 1e-6f);
  // regular stores: L2 merges the half-line pairs into full-line writebacks
  *(float4*)(oW1 + off)     = make_float4(t1[0]*r1, t1[1]*r1, t1[2]*r1, t1[3]*r1);
  *(float4*)(oW1 + off + 4) = make_float4(t1[4]*r1, t1[5]*r1, t1[6]*r1, t1[7]*r1);
  *(float4*)(oW2 + off)     = make_float4(t2[0]*r2, t2[1]*r2, t2[2]*r2, t2[3]*r2);
  *(float4*)(oW2 + off + 4) = make_float4(t2[4]*r2, t2[5]*r2, t2[6]*r2, t2[7]*r2);
  *(float4*)(oW3 + off)     = make_float4(t3[0]*r3, t3[1]*r3, t3[2]*r3, t3[3]*r3);
  *(float4*)(oW3 + off + 4) = make_float4(t3[4]*r3, t3[5]*r3, t3[6]*r3, t3[7]*r3);
}

__global__ __launch_bounds__(512) void k3_update(
    const int* __restrict__ flag,
    const float* __restrict__ errw, const float* __restrict__ plw,
    const void* __restrict__ state, const void* __restrict__ n1raw,
    const void* __restrict__ n2raw,
    const float* __restrict__ mag, const float* __restrict__ stats,
    const int* __restrict__ stepc,
    const void* __restrict__ W1, const void* __restrict__ W2,
    const void* __restrict__ W3,
    const void* __restrict__ M1, const void* __restrict__ M2,
    const void* __restrict__ M3,
    float* __restrict__ oW1, float* __restrict__ oW2, float* __restrict__ oW3)
{
  if (*flag) k3_body<true >(errw,plw,state,n1raw,n2raw,mag,stats,stepc,W1,W2,W3,M1,M2,M3,oW1,oW2,oW3);
  else       k3_body<false>(errw,plw,state,n1raw,n2raw,mag,stats,stepc,W1,W2,W3,M1,M2,M3,oW1,oW2,oW3);
}

extern "C" void kernel_launch(void* const* d_in, const int* in_sizes, int n_in,
                              void* d_out, int out_size, void* d_ws, size_t ws_size,
                              hipStream_t stream) {
  const void* eye     = d_in[0];
  const void* stomach = d_in[1];
  const void* state   = d_in[2];
  const void* outp    = d_in[3];
  const void* W1      = d_in[4];
  const void* W2      = d_in[5];
  const void* W3      = d_in[6];
  const void* M1      = d_in[7];
  const void* M2      = d_in[8];
  const void* M3      = d_in[9];
  const void* Ebase   = d_in[10];
  const void* Aold    = d_in[11];
  const void* noiseA  = d_in[12];
  const void* n1raw   = d_in[13];
  const void* n2raw   = d_in[14];
  const int*  stepc   = (const int*)d_in[15];

  float* ws    = (float*)d_ws;
  float* qw    = ws;
  float* kw    = ws + 131072;
  float* errw  = ws + 262144;
  float* plw   = ws + 393216;
  float* magn  = ws + 524288;   // per-node |state| sums (2048)
  float* mag   = ws + 526336;   // per-batch sums (16)
  float* stats = ws + 526352;
  int*   flag  = (int*)(ws + 526354);

  float* out        = (float*)d_out;
  float* out_pred   = out;                 // (B,N,D)
  float* out_target = out + 131072;        // (B,N,D)
  float* out_A      = out + 262144;        // (B,N,N)
  float* oW1        = out + 524288;        // (B,N,D,D)
  float* oW2        = out + 8912896;
  float* oW3        = out + 17301504;

  // no memset: stats zeroed by k1 (precedes k2's atomics in-stream);
  // magn/mag/flag are fully overwritten each iteration.
  k1_qkpred<<<1536, 256, 0, stream>>>(state, W1, W2, W3, qw, kw, magn, out_pred,
                                      flag, stats);
  k2_attn<<<512, 256, 0, stream>>>(flag, qw, kw, out_pred, noiseA, Aold, outp,
                                   eye, stomach, Ebase, magn, mag, errw, plw, stats,
                                   out_target, out_A);
  k3_update<<<2048, 512, 0, stream>>>(flag, errw, plw, state, n1raw, n2raw, mag, stats,
                                      stepc, W1, W2, W3, M1, M2, M3, oW1, oW2, oW3);
}